// Round 18
// baseline (284.340 us; speedup 1.0000x reference)
//
#include <hip/hip_runtime.h>
#include <hip/hip_bf16.h>

#define NROW_F 8192
#define NROW_B 65536
#define KDIM   384
#define BM 128
#define BN 128
#define NSUB 16
#define NGRP (NROW_B / (BN * NSUB))      // 32
#define NBM  (NROW_F / BM)               // 64
#define NWG  (NBM * NGRP)                // 2048

// LDS (80 KB -> 2 blocks/CU):
//   [0, 48K)  A staging (prologue only); after A->regs the region is dead:
//             sB slice lives at [0, 8K), epilogue red[] at [16K, 17K).
//   [48K,80K) B quad-buffer 4 x 8K.
#define LDSA 0
#define LDSS2 0
#define LDSR2 16384
#define LDSB 49152
#define LDS_TOT 81920

typedef int   i32x4 __attribute__((ext_vector_type(4)));
typedef float f32x4 __attribute__((ext_vector_type(4)));

static __device__ __forceinline__ void stage16(const void* g, void* l) {
  __builtin_amdgcn_global_load_lds(
      (const __attribute__((address_space(1))) unsigned int*)g,
      (__attribute__((address_space(3))) unsigned int*)l, 16, 0, 0);
}

// ---------------------------------------------------------------------------
// 1) L2-normalize + i8 quantize, bank AND features in one launch.
//    Half-wave per row, float4 loads / char4 stores.
// ---------------------------------------------------------------------------
__global__ __launch_bounds__(256) void quantize_all_kernel(
    const float* __restrict__ bank, char* __restrict__ mb8, float* __restrict__ sB,
    const float* __restrict__ feat, char* __restrict__ f8, float* __restrict__ sA) {
  const float* in; char* out8; float* scales; int row;
  if (blockIdx.x < NROW_B / 8) {
    in = bank; out8 = mb8; scales = sB;
    row = blockIdx.x * 8 + (threadIdx.x >> 5);
  } else {
    in = feat; out8 = f8; scales = sA;
    row = (blockIdx.x - NROW_B / 8) * 8 + (threadIdx.x >> 5);
  }
  int l = threadIdx.x & 31;
  const f32x4* r = (const f32x4*)(in + (size_t)row * KDIM);
  f32x4 v[3];
  float ss = 0.f, mx = 0.f;
#pragma unroll
  for (int i = 0; i < 3; ++i) {
    v[i] = r[l + i * 32];
#pragma unroll
    for (int j = 0; j < 4; ++j) {
      ss += v[i][j] * v[i][j];
      mx = fmaxf(mx, fabsf(v[i][j]));
    }
  }
#pragma unroll
  for (int d = 1; d < 32; d <<= 1) {
    ss += __shfl_xor(ss, d, 64);
    mx = fmaxf(mx, __shfl_xor(mx, d, 64));
  }
  mx = fmaxf(mx, 1e-30f);
  float inv = rsqrtf(fmaxf(ss, 1e-24f));
  float scl = 127.0f / mx;
  if (l == 0) scales[row] = mx * inv * (1.0f / 127.0f);
  char* o = out8 + (size_t)row * KDIM;
#pragma unroll
  for (int i = 0; i < 3; ++i) {
    char4 c;
    c.x = (char)__float2int_rn(v[i][0] * scl);
    c.y = (char)__float2int_rn(v[i][1] * scl);
    c.z = (char)__float2int_rn(v[i][2] * scl);
    c.w = (char)__float2int_rn(v[i][3] * scl);
    *(char4*)(o + (l + i * 32) * 4) = c;
  }
}

// ---------------------------------------------------------------------------
// 2) maxsim: i8 MFMA 16x16x64, A in regs, B QUAD-buffered, uniform vmcnt(4).
//    r16's tri-buf had B in flight only ~1.7 phases (~800cy) < HBM 900cy;
//    4-deep gives ~2.7 phases (~1280cy). sB moved into the dead A region.
//    Phase t: vmcnt(4) [B(t+1) landed] -> bar -> read B(t+1) regs + stage
//    B(t+4)->buf t&3 -> 16 MFMA (no wait) -> lgkm(0). 12-phase unroll
//    (t = 6*sub+off, 6*even ≡ 0 mod 4 so buf literals repeat per 2 subtiles).
// ---------------------------------------------------------------------------
__global__ __launch_bounds__(256, 2) void maxsim_kernel(
    const char* __restrict__ F8,    // 8192 x 384 i8
    const char* __restrict__ B8,    // 65536 x 384 i8
    const float* __restrict__ sA,   // 8192
    const float* __restrict__ sB,   // 65536
    float* __restrict__ partial) {  // NGRP x 8192 (max sim)
  __shared__ __align__(16) char smem[LDS_TOT];

  const int tid  = threadIdx.x;
  const int wv   = tid >> 6;         // 0..3
  const int lane = tid & 63;
  const int l15  = lane & 15;
  const int lhi  = lane >> 4;
  const int wr   = wv >> 1;          // 0..1 (row half)
  const int wc   = wv & 1;           // 0..1 (col half)

  const int wg  = (blockIdx.x & 7) * (NWG / 8) + (blockIdx.x >> 3);
  const int bm  = wg & (NBM - 1);
  const int grp = wg >> 6;
  const size_t brow = (size_t)bm * BM;

  const int srow = tid >> 2;                           // 0..63
  const int gsw  = (tid & 3) ^ ((tid >> 3) & 3);       // inverse write swizzle

  // ---- prologue step 1: stage A (12 issues), drain, A -> registers ----
  {
    const char* gA = F8 + (size_t)(brow + srow) * KDIM + gsw * 16;
    char* lA = smem + LDSA + wv * 1024;
#pragma unroll
    for (int kt = 0; kt < 6; ++kt) {
      stage16(gA + kt * 64,             lA + kt * 8192);
      stage16(gA + kt * 64 + 64 * KDIM, lA + kt * 8192 + 4096);
    }
  }
  asm volatile("s_waitcnt vmcnt(0)" ::: "memory");
  __builtin_amdgcn_s_barrier();

  const int cof = ((l15 >> 1) & 3) << 4;
  auto ldA8 = [&](int k6, int m) -> i32x4 {
    int byte = k6 * 8192 + (wr * 64 + m * 16 + l15) * 64 + ((lhi << 4) ^ cof);
    return *reinterpret_cast<const i32x4*>(smem + LDSA + byte);
  };
  i32x4 a[6][4];
#pragma unroll
  for (int k6 = 0; k6 < 6; ++k6)
#pragma unroll
    for (int m = 0; m < 4; ++m) a[k6][m] = ldA8(k6, m);
  asm volatile("s_waitcnt lgkmcnt(0)" ::: "memory");
  __builtin_amdgcn_s_barrier();   // ALL waves done reading A region

  // ---- prologue step 2: sB into dead A region, then B0..B3 ----
  {
    const char* gs = (const char*)(sB + (size_t)grp * 2048) + tid * 16;
    stage16(gs,        smem + LDSS2 + wv * 1024);
    stage16(gs + 4096, smem + LDSS2 + 4096 + wv * 1024);
  }
  auto stageB = [&](int s2, int koff, int buf) {
    const char* g = B8 + ((size_t)grp * 2048 + s2 * 128 + srow) * KDIM
                    + koff * 64 + gsw * 16;
    char* l = smem + LDSB + buf * 8192 + wv * 1024;
    stage16(g, l);
    stage16(g + (size_t)64 * KDIM, l + 4096);
  };
  stageB(0, 0, 0);
  stageB(0, 1, 1);
  stageB(0, 2, 2);
  stageB(0, 3, 3);

  auto ldB8 = [&](int buf, int n) -> i32x4 {
    int byte = buf * 8192 + (wc * 64 + n * 16 + l15) * 64 + ((lhi << 4) ^ cof);
    return *reinterpret_cast<const i32x4*>(smem + LDSB + byte);
  };

  i32x4 acc[4][4];
  f32x4 vm[4];
#pragma unroll
  for (int m = 0; m < 4; ++m) {
    vm[m] = f32x4{-1e30f, -1e30f, -1e30f, -1e30f};
#pragma unroll
    for (int n = 0; n < 4; ++n) acc[m][n] = i32x4{0, 0, 0, 0};
  }

  // outstanding: sB(2), B0..B3(8) = 10; vmcnt(6) retires sB + B0.
  asm volatile("s_waitcnt vmcnt(6)" ::: "memory");
  __builtin_amdgcn_s_barrier();

  i32x4 bA[4], bB[4];
#pragma unroll
  for (int n = 0; n < 4; ++n) bA[n] = ldB8(0, n);
  asm volatile("s_waitcnt lgkmcnt(0)" ::: "memory");
  // entering loop: outstanding = B1,B2,B3 = 6 issues.

#define PHASE(K6, SUBX, RB, SBUF, BC, BN_) do {                               \
    asm volatile("s_waitcnt vmcnt(4)" ::: "memory");  /* B(t+1) landed */     \
    __builtin_amdgcn_s_barrier();                                             \
    __builtin_amdgcn_sched_barrier(0);                                        \
    _Pragma("unroll")                                                         \
    for (int n = 0; n < 4; ++n) BN_[n] = ldB8(RB, n);                         \
    stageB(((K6) < 2) ? (SUBX) : (((SUBX) + 1) & (NSUB - 1)),                 \
           ((K6) + 4) % 6, SBUF);                                             \
    __builtin_amdgcn_sched_barrier(0);                                        \
    __builtin_amdgcn_s_setprio(1);                                            \
    _Pragma("unroll")                                                         \
    for (int n = 0; n < 4; ++n)                                               \
      _Pragma("unroll")                                                       \
      for (int m = 0; m < 4; ++m)                                             \
        acc[m][n] = __builtin_amdgcn_mfma_i32_16x16x64_i8(                    \
            a[K6][m], BC[n], acc[m][n], 0, 0, 0);                             \
    __builtin_amdgcn_s_setprio(0);                                            \
    asm volatile("s_waitcnt lgkmcnt(0)" ::: "memory");                        \
    __builtin_amdgcn_sched_barrier(0);                                        \
  } while (0)

#define FOLD(S) do {                                                          \
    float sb[4];                                                              \
    _Pragma("unroll")                                                         \
    for (int n = 0; n < 4; ++n)                                               \
      sb[n] = *reinterpret_cast<const float*>(                                \
          smem + LDSS2 + ((S) * 128 + wc * 64 + n * 16 + l15) * 4);           \
    _Pragma("unroll")                                                         \
    for (int m = 0; m < 4; ++m) {                                             \
      _Pragma("unroll")                                                       \
      for (int n = 0; n < 4; ++n)                                             \
        _Pragma("unroll")                                                     \
        for (int j = 0; j < 4; ++j)                                           \
          vm[m][j] = fmaxf(vm[m][j], (float)acc[m][n][j] * sb[n]);            \
      _Pragma("unroll")                                                       \
      for (int n = 0; n < 4; ++n) acc[m][n] = i32x4{0, 0, 0, 0};              \
    }                                                                         \
  } while (0)

  for (int sub = 0; sub < NSUB; sub += 2) {
    PHASE(0, sub, 1, 0, bA, bB);
    PHASE(1, sub, 2, 1, bB, bA);
    PHASE(2, sub, 3, 2, bA, bB);
    PHASE(3, sub, 0, 3, bB, bA);
    PHASE(4, sub, 1, 0, bA, bB);
    PHASE(5, sub, 2, 1, bB, bA);
    FOLD(sub);
    PHASE(0, sub + 1, 3, 2, bA, bB);
    PHASE(1, sub + 1, 0, 3, bB, bA);
    PHASE(2, sub + 1, 1, 0, bA, bB);
    PHASE(3, sub + 1, 2, 1, bB, bA);
    PHASE(4, sub + 1, 3, 2, bA, bB);
    PHASE(5, sub + 1, 0, 3, bB, bA);
    FOLD(sub + 1);
  }
#undef PHASE
#undef FOLD

  // ---- epilogue ----
  asm volatile("s_waitcnt vmcnt(0)" ::: "memory");
#pragma unroll
  for (int d = 1; d < 16; d <<= 1)
#pragma unroll
    for (int m = 0; m < 4; ++m)
#pragma unroll
      for (int j = 0; j < 4; ++j)
        vm[m][j] = fmaxf(vm[m][j], __shfl_xor(vm[m][j], d, 64));

  float* red = (float*)(smem + LDSR2);   // in dead A region (past sB slice)
  __syncthreads();
  if (l15 == 0) {
#pragma unroll
    for (int m = 0; m < 4; ++m)
#pragma unroll
      for (int j = 0; j < 4; ++j)
        red[wc * 128 + wr * 64 + m * 16 + lhi * 4 + j] = vm[m][j];
  }
  __syncthreads();
  if (tid < BM) {
    float x = fmaxf(red[tid], red[128 + tid]);
    partial[(size_t)grp * NROW_F + brow + tid] = x * sA[brow + tid];
  }
}

// ---------------------------------------------------------------------------
// 3) fused: combine (blocks 0..31) + build W (32..87) + top-10 (88..95).
// ---------------------------------------------------------------------------
__global__ __launch_bounds__(256) void combw_topk_kernel(
    const float* __restrict__ partial, float* __restrict__ md,
    float* __restrict__ W, float* __restrict__ out) {
  if (blockIdx.x < 32) {
    int r = blockIdx.x * 256 + threadIdx.x;
    float m = -1e30f;
#pragma unroll
    for (int c = 0; c < NGRP; ++c) m = fmaxf(m, partial[(size_t)c * NROW_F + r]);
    float d = 1.0f - m;
    md[r] = fminf(fmaxf(d, 0.0f), 2.0f);
    return;
  }
  if (blockIdx.x < 88) {
    int idx = (blockIdx.x - 32) * 256 + threadIdx.x;   // < 14336
    int y = idx >> 5, g = idx & 31;
    float ksum = 0.f, acc = 0.f;
#pragma unroll
    for (int t = -16; t <= 16; ++t) {
      float ft = (float)t * 0.25f;
      float kv = expf(-0.5f * ft * ft);
      ksum += kv;
      int p = y + t;
      p = (p < 0) ? -p : ((p > 447) ? 894 - p : p);
      float src = ((float)p + 0.5f) * (1.0f / 14.0f) - 0.5f;
      float fl = floorf(src);
      int i0 = (int)fl;
      float fr = src - fl;
      int c0 = i0 < 0 ? 0 : (i0 > 31 ? 31 : i0);
      int i1 = i0 + 1;
      int c1 = i1 < 0 ? 0 : (i1 > 31 ? 31 : i1);
      float w = 0.f;
      if (c0 == g) w += 1.0f - fr;
      if (c1 == g) w += fr;
      acc += kv * w;
    }
    W[idx] = acc / ksum;
    return;
  }
  // top-10 mean: one wave per batch, register-resident, shuffle-only.
  if (threadIdx.x >= 64) return;
  int b = blockIdx.x - 88, lane = threadIdx.x;
  float vals[16];
#pragma unroll
  for (int k = 0; k < 16; ++k) {
    int r = b * 1024 + k * 64 + lane;
    float m = -1e30f;
#pragma unroll
    for (int c = 0; c < NGRP; ++c) m = fmaxf(m, partial[(size_t)c * NROW_F + r]);
    float d = 1.0f - m;
    vals[k] = fminf(fmaxf(d, 0.0f), 2.0f);
  }
  float total = 0.f;
  for (int it = 0; it < 10; ++it) {
    float lb = vals[0]; int li = 0;
#pragma unroll
    for (int k = 1; k < 16; ++k)
      if (vals[k] > lb) { lb = vals[k]; li = k; }
    float wm = lb;
#pragma unroll
    for (int d = 1; d < 64; d <<= 1) wm = fmaxf(wm, __shfl_xor(wm, d, 64));
    unsigned long long mask = __ballot(lb == wm);
    int winner = (int)(__ffsll(mask) - 1);
    bool kill = (lane == winner);
#pragma unroll
    for (int k = 0; k < 16; ++k)
      vals[k] = (kill && k == li) ? -1e30f : vals[k];
    total += wm;
  }
  if (lane == 0) out[b] = total * 0.1f;
}

// ---------------------------------------------------------------------------
// 4) anomaly_map = W · md_grid · W^T, one block per (b, y).
// ---------------------------------------------------------------------------
__global__ __launch_bounds__(256) void map_kernel(
    const float* __restrict__ md, const float* __restrict__ W,
    float* __restrict__ out) {  // 8 x 448 x 448
  __shared__ float tmpv[32];
  int y = blockIdx.x % 448;
  int b = blockIdx.x / 448;
  int tid = threadIdx.x;
  if (tid < 32) {
    const float* w = W + y * 32;
    const float* m = md + b * 1024 + tid;
    float s = 0.f;
#pragma unroll
    for (int gy = 0; gy < 32; ++gy) s += w[gy] * m[gy * 32];
    tmpv[tid] = s;
  }
  __syncthreads();
  for (int x = tid; x < 448; x += 256) {
    const float* w = W + x * 32;
    float s = 0.f;
#pragma unroll
    for (int gx = 0; gx < 32; ++gx) s += w[gx] * tmpv[gx];
    out[(size_t)blockIdx.x * 448 + x] = s;
  }
}

// ---------------------------------------------------------------------------
extern "C" void kernel_launch(void* const* d_in, const int* in_sizes, int n_in,
                              void* d_out, int out_size, void* d_ws, size_t ws_size,
                              hipStream_t stream) {
  const float* features = (const float*)d_in[0];   // 8*1024*384
  const float* bank     = (const float*)d_in[1];   // 65536*384
  float* out = (float*)d_out;                      // [8 scores][8*448*448 map]

  char* ws = (char*)d_ws;
  char*  mb8     = ws;                              // 25,165,824 B
  char*  f8      = ws + 25165824;                   //  3,145,728 B
  float* sB      = (float*)(ws + 28311552);         //    262,144 B
  float* sA      = (float*)(ws + 28573696);         //     32,768 B
  float* partial = (float*)(ws + 28606464);         //  1,048,576 B
  float* md      = (float*)(ws + 29655040);         //     32,768 B
  float* W       = (float*)(ws + 29687808);         //     57,344 B

  quantize_all_kernel<<<(NROW_B + NROW_F) / 8, 256, 0, stream>>>(
      bank, mb8, sB, features, f8, sA);
  maxsim_kernel<<<NWG, 256, 0, stream>>>(f8, mb8, sA, sB, partial);
  combw_topk_kernel<<<96, 256, 0, stream>>>(partial, md, W, out);
  map_kernel<<<8 * 448, 256, 0, stream>>>(md, W, out + 8);
}

// Round 19
// 239.600 us; speedup vs baseline: 1.1867x; 1.1867x over previous
//
#include <hip/hip_runtime.h>
#include <hip/hip_bf16.h>

#define NROW_F 8192
#define NROW_B 65536
#define KDIM   384
#define BM 128
#define BN 128
#define NSUB 16
#define NGRP (NROW_B / (BN * NSUB))      // 32
#define NBM  (NROW_F / BM)               // 64
#define NWG  (NBM * NGRP)                // 2048

// LDS (80 KB -> 2 blocks/CU):
//   [0, 48K)  A staging (prologue only); after A->regs: sB at [0,8K),
//             epilogue red[] at [16K,17K).
//   [48K,80K) B quad-buffer 4 x 8K.
#define LDSA 0
#define LDSS2 0
#define LDSR2 16384
#define LDSB 49152
#define LDS_TOT 81920

typedef int   i32x4 __attribute__((ext_vector_type(4)));
typedef float f32x4 __attribute__((ext_vector_type(4)));

static __device__ __forceinline__ void stage16(const void* g, void* l) {
  __builtin_amdgcn_global_load_lds(
      (const __attribute__((address_space(1))) unsigned int*)g,
      (__attribute__((address_space(3))) unsigned int*)l, 16, 0, 0);
}

// ---------------------------------------------------------------------------
// 1) L2-normalize rows + symmetric i8 quantization with per-row scale.
//    Half-wave (32 lanes) per row, float4 loads / char4 stores (r17 tail).
// ---------------------------------------------------------------------------
__global__ __launch_bounds__(256) void quantize_rows_kernel(
    const float* __restrict__ in, char* __restrict__ out8,
    float* __restrict__ scales, int nrows) {
  int row = blockIdx.x * 8 + (threadIdx.x >> 5);
  int l   = threadIdx.x & 31;
  if (row >= nrows) return;
  const f32x4* r = (const f32x4*)(in + (size_t)row * KDIM);
  f32x4 v[3];
  float ss = 0.f, mx = 0.f;
#pragma unroll
  for (int i = 0; i < 3; ++i) {
    v[i] = r[l + i * 32];
#pragma unroll
    for (int j = 0; j < 4; ++j) {
      ss += v[i][j] * v[i][j];
      mx = fmaxf(mx, fabsf(v[i][j]));
    }
  }
#pragma unroll
  for (int d = 1; d < 32; d <<= 1) {
    ss += __shfl_xor(ss, d, 64);
    mx = fmaxf(mx, __shfl_xor(mx, d, 64));
  }
  mx = fmaxf(mx, 1e-30f);
  float inv = rsqrtf(fmaxf(ss, 1e-24f));
  float scl = 127.0f / mx;
  if (l == 0) scales[row] = mx * inv * (1.0f / 127.0f);
  char* o = out8 + (size_t)row * KDIM;
#pragma unroll
  for (int i = 0; i < 3; ++i) {
    char4 c;
    c.x = (char)__float2int_rn(v[i][0] * scl);
    c.y = (char)__float2int_rn(v[i][1] * scl);
    c.z = (char)__float2int_rn(v[i][2] * scl);
    c.w = (char)__float2int_rn(v[i][3] * scl);
    *(char4*)(o + (l + i * 32) * 4) = c;
  }
}

// ---------------------------------------------------------------------------
// 2) maxsim: r18 version (quad-buffered B, uniform vmcnt(4)) — 180.7 us.
// ---------------------------------------------------------------------------
__global__ __launch_bounds__(256, 2) void maxsim_kernel(
    const char* __restrict__ F8,    // 8192 x 384 i8
    const char* __restrict__ B8,    // 65536 x 384 i8
    const float* __restrict__ sA,   // 8192
    const float* __restrict__ sB,   // 65536
    float* __restrict__ partial) {  // NGRP x 8192 (max sim)
  __shared__ __align__(16) char smem[LDS_TOT];

  const int tid  = threadIdx.x;
  const int wv   = tid >> 6;         // 0..3
  const int lane = tid & 63;
  const int l15  = lane & 15;
  const int lhi  = lane >> 4;
  const int wr   = wv >> 1;          // 0..1 (row half)
  const int wc   = wv & 1;           // 0..1 (col half)

  const int wg  = (blockIdx.x & 7) * (NWG / 8) + (blockIdx.x >> 3);
  const int bm  = wg & (NBM - 1);
  const int grp = wg >> 6;
  const size_t brow = (size_t)bm * BM;

  const int srow = tid >> 2;                           // 0..63
  const int gsw  = (tid & 3) ^ ((tid >> 3) & 3);       // inverse write swizzle

  // ---- prologue step 1: stage A (12 issues), drain, A -> registers ----
  {
    const char* gA = F8 + (size_t)(brow + srow) * KDIM + gsw * 16;
    char* lA = smem + LDSA + wv * 1024;
#pragma unroll
    for (int kt = 0; kt < 6; ++kt) {
      stage16(gA + kt * 64,             lA + kt * 8192);
      stage16(gA + kt * 64 + 64 * KDIM, lA + kt * 8192 + 4096);
    }
  }
  asm volatile("s_waitcnt vmcnt(0)" ::: "memory");
  __builtin_amdgcn_s_barrier();

  const int cof = ((l15 >> 1) & 3) << 4;
  auto ldA8 = [&](int k6, int m) -> i32x4 {
    int byte = k6 * 8192 + (wr * 64 + m * 16 + l15) * 64 + ((lhi << 4) ^ cof);
    return *reinterpret_cast<const i32x4*>(smem + LDSA + byte);
  };
  i32x4 a[6][4];
#pragma unroll
  for (int k6 = 0; k6 < 6; ++k6)
#pragma unroll
    for (int m = 0; m < 4; ++m) a[k6][m] = ldA8(k6, m);
  asm volatile("s_waitcnt lgkmcnt(0)" ::: "memory");
  __builtin_amdgcn_s_barrier();   // ALL waves done reading A region

  // ---- prologue step 2: sB into dead A region, then B0..B3 ----
  {
    const char* gs = (const char*)(sB + (size_t)grp * 2048) + tid * 16;
    stage16(gs,        smem + LDSS2 + wv * 1024);
    stage16(gs + 4096, smem + LDSS2 + 4096 + wv * 1024);
  }
  auto stageB = [&](int s2, int koff, int buf) {
    const char* g = B8 + ((size_t)grp * 2048 + s2 * 128 + srow) * KDIM
                    + koff * 64 + gsw * 16;
    char* l = smem + LDSB + buf * 8192 + wv * 1024;
    stage16(g, l);
    stage16(g + (size_t)64 * KDIM, l + 4096);
  };
  stageB(0, 0, 0);
  stageB(0, 1, 1);
  stageB(0, 2, 2);
  stageB(0, 3, 3);

  auto ldB8 = [&](int buf, int n) -> i32x4 {
    int byte = buf * 8192 + (wc * 64 + n * 16 + l15) * 64 + ((lhi << 4) ^ cof);
    return *reinterpret_cast<const i32x4*>(smem + LDSB + byte);
  };

  i32x4 acc[4][4];
  f32x4 vm[4];
#pragma unroll
  for (int m = 0; m < 4; ++m) {
    vm[m] = f32x4{-1e30f, -1e30f, -1e30f, -1e30f};
#pragma unroll
    for (int n = 0; n < 4; ++n) acc[m][n] = i32x4{0, 0, 0, 0};
  }

  // outstanding: sB(2), B0..B3(8) = 10; vmcnt(6) retires sB + B0.
  asm volatile("s_waitcnt vmcnt(6)" ::: "memory");
  __builtin_amdgcn_s_barrier();

  i32x4 bA[4], bB[4];
#pragma unroll
  for (int n = 0; n < 4; ++n) bA[n] = ldB8(0, n);
  asm volatile("s_waitcnt lgkmcnt(0)" ::: "memory");
  // entering loop: outstanding = B1,B2,B3 = 6 issues.

#define PHASE(K6, SUBX, RB, SBUF, BC, BN_) do {                               \
    asm volatile("s_waitcnt vmcnt(4)" ::: "memory");  /* B(t+1) landed */     \
    __builtin_amdgcn_s_barrier();                                             \
    __builtin_amdgcn_sched_barrier(0);                                        \
    _Pragma("unroll")                                                         \
    for (int n = 0; n < 4; ++n) BN_[n] = ldB8(RB, n);                         \
    stageB(((K6) < 2) ? (SUBX) : (((SUBX) + 1) & (NSUB - 1)),                 \
           ((K6) + 4) % 6, SBUF);                                             \
    __builtin_amdgcn_sched_barrier(0);                                        \
    __builtin_amdgcn_s_setprio(1);                                            \
    _Pragma("unroll")                                                         \
    for (int n = 0; n < 4; ++n)                                               \
      _Pragma("unroll")                                                       \
      for (int m = 0; m < 4; ++m)                                             \
        acc[m][n] = __builtin_amdgcn_mfma_i32_16x16x64_i8(                    \
            a[K6][m], BC[n], acc[m][n], 0, 0, 0);                             \
    __builtin_amdgcn_s_setprio(0);                                            \
    asm volatile("s_waitcnt lgkmcnt(0)" ::: "memory");                        \
    __builtin_amdgcn_sched_barrier(0);                                        \
  } while (0)

#define FOLD(S) do {                                                          \
    float sb[4];                                                              \
    _Pragma("unroll")                                                         \
    for (int n = 0; n < 4; ++n)                                               \
      sb[n] = *reinterpret_cast<const float*>(                                \
          smem + LDSS2 + ((S) * 128 + wc * 64 + n * 16 + l15) * 4);           \
    _Pragma("unroll")                                                         \
    for (int m = 0; m < 4; ++m) {                                             \
      _Pragma("unroll")                                                       \
      for (int n = 0; n < 4; ++n)                                             \
        _Pragma("unroll")                                                     \
        for (int j = 0; j < 4; ++j)                                           \
          vm[m][j] = fmaxf(vm[m][j], (float)acc[m][n][j] * sb[n]);            \
      _Pragma("unroll")                                                       \
      for (int n = 0; n < 4; ++n) acc[m][n] = i32x4{0, 0, 0, 0};              \
    }                                                                         \
  } while (0)

  for (int sub = 0; sub < NSUB; sub += 2) {
    PHASE(0, sub, 1, 0, bA, bB);
    PHASE(1, sub, 2, 1, bB, bA);
    PHASE(2, sub, 3, 2, bA, bB);
    PHASE(3, sub, 0, 3, bB, bA);
    PHASE(4, sub, 1, 0, bA, bB);
    PHASE(5, sub, 2, 1, bB, bA);
    FOLD(sub);
    PHASE(0, sub + 1, 3, 2, bA, bB);
    PHASE(1, sub + 1, 0, 3, bB, bA);
    PHASE(2, sub + 1, 1, 0, bA, bB);
    PHASE(3, sub + 1, 2, 1, bB, bA);
    PHASE(4, sub + 1, 3, 2, bA, bB);
    PHASE(5, sub + 1, 0, 3, bB, bA);
    FOLD(sub + 1);
  }
#undef PHASE
#undef FOLD

  // ---- epilogue ----
  asm volatile("s_waitcnt vmcnt(0)" ::: "memory");
#pragma unroll
  for (int d = 1; d < 16; d <<= 1)
#pragma unroll
    for (int m = 0; m < 4; ++m)
#pragma unroll
      for (int j = 0; j < 4; ++j)
        vm[m][j] = fmaxf(vm[m][j], __shfl_xor(vm[m][j], d, 64));

  float* red = (float*)(smem + LDSR2);
  __syncthreads();
  if (l15 == 0) {
#pragma unroll
    for (int m = 0; m < 4; ++m)
#pragma unroll
      for (int j = 0; j < 4; ++j)
        red[wc * 128 + wr * 64 + m * 16 + lhi * 4 + j] = vm[m][j];
  }
  __syncthreads();
  if (tid < BM) {
    float x = fmaxf(red[tid], red[128 + tid]);
    partial[(size_t)grp * NROW_F + brow + tid] = x * sA[brow + tid];
  }
}

// ---------------------------------------------------------------------------
// 3) combine (blocks 0..31) + build W (blocks 32..87) fused (r17 tail).
// ---------------------------------------------------------------------------
__global__ __launch_bounds__(256) void combw_kernel(
    const float* __restrict__ partial, float* __restrict__ md,
    float* __restrict__ W) {
  if (blockIdx.x < 32) {
    int r = blockIdx.x * 256 + threadIdx.x;
    float m = -1e30f;
#pragma unroll
    for (int c = 0; c < NGRP; ++c) m = fmaxf(m, partial[(size_t)c * NROW_F + r]);
    float d = 1.0f - m;
    md[r] = fminf(fmaxf(d, 0.0f), 2.0f);
    return;
  }
  int idx = (blockIdx.x - 32) * 256 + threadIdx.x;   // < 448*32 = 14336
  int y = idx >> 5, g = idx & 31;
  float ksum = 0.f, acc = 0.f;
#pragma unroll
  for (int t = -16; t <= 16; ++t) {
    float ft = (float)t * 0.25f;
    float kv = expf(-0.5f * ft * ft);
    ksum += kv;
    int p = y + t;
    p = (p < 0) ? -p : ((p > 447) ? 894 - p : p);
    float src = ((float)p + 0.5f) * (1.0f / 14.0f) - 0.5f;
    float fl = floorf(src);
    int i0 = (int)fl;
    float fr = src - fl;
    int c0 = i0 < 0 ? 0 : (i0 > 31 ? 31 : i0);
    int i1 = i0 + 1;
    int c1 = i1 < 0 ? 0 : (i1 > 31 ? 31 : i1);
    float w = 0.f;
    if (c0 == g) w += 1.0f - fr;
    if (c1 == g) w += fr;
    acc += kv * w;
  }
  W[idx] = acc / ksum;
}

// ---------------------------------------------------------------------------
// 4) top-10 mean per batch (r17 tail): 1 wave, register-resident, shuffles.
// ---------------------------------------------------------------------------
__global__ __launch_bounds__(64) void topk_kernel(
    const float* __restrict__ partial, float* __restrict__ out) {
  int b = blockIdx.x, lane = threadIdx.x;
  float vals[16];
#pragma unroll
  for (int k = 0; k < 16; ++k) {
    int r = b * 1024 + k * 64 + lane;
    float m = -1e30f;
#pragma unroll
    for (int c = 0; c < NGRP; ++c) m = fmaxf(m, partial[(size_t)c * NROW_F + r]);
    float d = 1.0f - m;
    vals[k] = fminf(fmaxf(d, 0.0f), 2.0f);
  }
  float total = 0.f;
  for (int it = 0; it < 10; ++it) {
    float lb = vals[0]; int li = 0;
#pragma unroll
    for (int k = 1; k < 16; ++k)
      if (vals[k] > lb) { lb = vals[k]; li = k; }
    float wm = lb;
#pragma unroll
    for (int d = 1; d < 64; d <<= 1) wm = fmaxf(wm, __shfl_xor(wm, d, 64));
    unsigned long long mask = __ballot(lb == wm);
    int winner = (int)(__ffsll(mask) - 1);
    bool kill = (lane == winner);
#pragma unroll
    for (int k = 0; k < 16; ++k)
      vals[k] = (kill && k == li) ? -1e30f : vals[k];
    total += wm;
  }
  if (lane == 0) out[b] = total * 0.1f;
}

// ---------------------------------------------------------------------------
// 5) anomaly_map = W · md_grid · W^T, one block per (b, y) (r17 tail).
// ---------------------------------------------------------------------------
__global__ __launch_bounds__(256) void map_kernel(
    const float* __restrict__ md, const float* __restrict__ W,
    float* __restrict__ out) {  // 8 x 448 x 448
  __shared__ float tmpv[32];
  int y = blockIdx.x % 448;
  int b = blockIdx.x / 448;
  int tid = threadIdx.x;
  if (tid < 32) {
    const float* w = W + y * 32;
    const float* m = md + b * 1024 + tid;
    float s = 0.f;
#pragma unroll
    for (int gy = 0; gy < 32; ++gy) s += w[gy] * m[gy * 32];
    tmpv[tid] = s;
  }
  __syncthreads();
  for (int x = tid; x < 448; x += 256) {
    const float* w = W + x * 32;
    float s = 0.f;
#pragma unroll
    for (int gx = 0; gx < 32; ++gx) s += w[gx] * tmpv[gx];
    out[(size_t)blockIdx.x * 448 + x] = s;
  }
}

// ---------------------------------------------------------------------------
extern "C" void kernel_launch(void* const* d_in, const int* in_sizes, int n_in,
                              void* d_out, int out_size, void* d_ws, size_t ws_size,
                              hipStream_t stream) {
  const float* features = (const float*)d_in[0];   // 8*1024*384
  const float* bank     = (const float*)d_in[1];   // 65536*384
  float* out = (float*)d_out;                      // [8 scores][8*448*448 map]

  char* ws = (char*)d_ws;
  char*  mb8     = ws;                              // 25,165,824 B
  char*  f8      = ws + 25165824;                   //  3,145,728 B
  float* sB      = (float*)(ws + 28311552);         //    262,144 B
  float* sA      = (float*)(ws + 28573696);         //     32,768 B
  float* partial = (float*)(ws + 28606464);         //  1,048,576 B
  float* md      = (float*)(ws + 29655040);         //     32,768 B
  float* W       = (float*)(ws + 29687808);         //     57,344 B

  quantize_rows_kernel<<<NROW_B / 8, 256, 0, stream>>>(bank, mb8, sB, NROW_B);
  quantize_rows_kernel<<<NROW_F / 8, 256, 0, stream>>>(features, f8, sA, NROW_F);
  maxsim_kernel<<<NWG, 256, 0, stream>>>(f8, mb8, sA, sB, partial);
  combw_kernel<<<88, 256, 0, stream>>>(partial, md, W);
  topk_kernel<<<8, 64, 0, stream>>>(partial, out);
  map_kernel<<<8 * 448, 256, 0, stream>>>(md, W, out + 8);
}